// Round 6
// baseline (361.575 us; speedup 1.0000x reference)
//
#include <hip/hip_runtime.h>

// Problem constants
constexpr int B    = 32;
constexpr int N    = 1568;
constexpr int N0   = 3136;
constexpr int Nt   = 784;
constexpr int Cin  = 256;
constexpr int Cout = 512;
constexpr int H    = 56;
constexpr int W    = 56;
constexpr int HW   = 3136;
constexpr int Ho   = 28;
constexpr int Wo   = 28;
constexpr int HWo  = 784;
constexpr int RR   = B * Nt;      // 25088 GEMM rows
constexpr int NE   = B * N0;      // 100352 entries per index list
constexpr int NBP  = B * HW;      // 100352 pixel bins
constexpr int NBT  = B * Nt;      // 25088 token bins
constexpr int NB   = NBP + NBT;   // 125440 bins
constexpr int NCHUNK = NB / 256;  // 490
constexpr size_t XTOT = (size_t)B * N * Cin;   // 12,845,056 x elements

// Workspace layout (4-byte words). hist + BN stats contiguous -> one memset.
constexpr size_t W_HIST  = 0;                         // NB ints (zeroed)
constexpr size_t W_S1SUM = NB;                        // 256
constexpr size_t W_S1SQ  = W_S1SUM + Cin;             // 256
constexpr size_t W_S2SUM = W_S1SQ + Cin;              // 512
constexpr size_t W_S2SQ  = W_S2SUM + Cout;            // 512 (memset region ends)
constexpr size_t W_OFF   = NB + 1536;                 // NB+1 ints (+pad)
constexpr size_t W_CUR   = W_OFF + NB + 8;            // NB ints
constexpr size_t W_P56   = W_CUR + NB;                // NE ints
constexpr size_t W_P28   = W_P56 + NE;                // NE ints
constexpr size_t W_BSUM  = W_P28 + NE;                // 512 ints
constexpr size_t W_SRTS  = W_BSUM + 512;              // NE ints
constexpr size_t W_STS   = W_SRTS + NE;               // NE ints
constexpr size_t W_STP   = W_STS + NE;                // NE ints
constexpr size_t W_STW   = W_STP + NE;                // NE floats
constexpr size_t W_CONVB = W_STW + NE;                // B*HWo*Cin bf16 -> /2 words
constexpr size_t W_YBF   = W_CONVB + (size_t)B * HWo * Cin / 2;  // RR*Cin bf16
constexpr size_t W_WFB   = W_YBF + (size_t)RR * Cin / 2;         // Cout*Cin bf16
constexpr size_t W_BIAS  = W_WFB + (size_t)Cout * Cin / 2;       // 512
constexpr size_t W_ZB    = W_BIAS + Cout;             // RR*Cout bf16 -> /2 words
constexpr size_t W_XH    = W_ZB + (size_t)RR * Cout / 2;  // XTOT bf16 -> /2 words

__device__ __forceinline__ int pix_of(float t, float scale) {
    t = fminf(fmaxf(t, -1.0f), 1.0f);
    float u = __fadd_rn(__fmul_rn(t, 0.5f), 0.5f);   // no fma contraction
    return (int)rintf(__fmul_rn(u, scale));          // round-half-even == jnp.round
}
__device__ __forceinline__ unsigned short f2bf(float f) {
    unsigned int u = __float_as_uint(f);
    u = (u + 0x7fffu + ((u >> 16) & 1u)) >> 16;      // RNE
    return (unsigned short)u;
}
__device__ __forceinline__ float bf2f(unsigned short h) {
    return __uint_as_float(((unsigned int)h) << 16);
}

// ---- cast x to bf16 ---------------------------------------------------------
__global__ void k_cast(const float* __restrict__ x, uint2* __restrict__ xh2) {
    size_t i = (size_t)blockIdx.x * 256 + threadIdx.x;   // 4 floats per thread
    float4 v = *(const float4*)&x[i * 4];
    uint2 o;
    o.x = (unsigned int)f2bf(v.x) | ((unsigned int)f2bf(v.y) << 16);
    o.y = (unsigned int)f2bf(v.z) | ((unsigned int)f2bf(v.w) << 16);
    xh2[i] = o;
}

// ---- sort phase -------------------------------------------------------------
__global__ void k_hist(const float* __restrict__ loc, const int* __restrict__ idxt,
                       int* __restrict__ hist, int* __restrict__ p56a, int* __restrict__ p28a) {
    int i = blockIdx.x * 256 + threadIdx.x;
    if (i >= NE) return;
    int b = i / N0;
    float lx = loc[(size_t)2 * i], ly = loc[(size_t)2 * i + 1];
    int p56 = pix_of(ly, 55.0f) * W + pix_of(lx, 55.0f);
    int p28 = pix_of(ly, 27.0f) * Wo + pix_of(lx, 27.0f);
    p56a[i] = p56; p28a[i] = p28;
    atomicAdd(&hist[b * HW + p56], 1);
    atomicAdd(&hist[NBP + b * Nt + idxt[i]], 1);
}

__global__ void k_scanA(const int* __restrict__ hist, int* __restrict__ bsum) {
    __shared__ int sm[256];
    int i = blockIdx.x * 256 + threadIdx.x;
    sm[threadIdx.x] = hist[i];
    __syncthreads();
    for (int d = 128; d > 0; d >>= 1) {
        if (threadIdx.x < d) sm[threadIdx.x] += sm[threadIdx.x + d];
        __syncthreads();
    }
    if (threadIdx.x == 0) bsum[blockIdx.x] = sm[0];
}

__global__ void k_scanB(int* __restrict__ bsum) {
    __shared__ int sm[512];
    int t = threadIdx.x;
    int v = (t < NCHUNK) ? bsum[t] : 0;
    sm[t] = v; __syncthreads();
    for (int d = 1; d < 512; d <<= 1) {
        int u = (t >= d) ? sm[t - d] : 0;
        __syncthreads();
        sm[t] += u;
        __syncthreads();
    }
    if (t < NCHUNK) bsum[t] = sm[t] - v;
}

__global__ void k_scanC(const int* __restrict__ hist, const int* __restrict__ bsum,
                        int* __restrict__ off, int* __restrict__ cur) {
    __shared__ int sm[256];
    int t = threadIdx.x;
    int i = blockIdx.x * 256 + t;
    int v = hist[i];
    sm[t] = v; __syncthreads();
    for (int d = 1; d < 256; d <<= 1) {
        int u = (t >= d) ? sm[t - d] : 0;
        __syncthreads();
        sm[t] += u;
        __syncthreads();
    }
    int excl = bsum[blockIdx.x] + sm[t] - v;
    off[i] = excl; cur[i] = excl;
    if (i == NB - 1) off[NB] = excl + v;
}

__global__ void k_scatteridx(const int* __restrict__ p56a, const int* __restrict__ p28a,
                             const int* __restrict__ idxa, const int* __restrict__ idxt,
                             const float* __restrict__ wt, int* __restrict__ cur,
                             int* __restrict__ srtS, int* __restrict__ sTs,
                             int* __restrict__ sTp, float* __restrict__ sTw) {
    int i = blockIdx.x * 256 + threadIdx.x;
    if (i >= NE) return;
    int b = i / N0;
    int s = idxa[i];
    int posP = atomicAdd(&cur[b * HW + p56a[i]], 1);
    srtS[posP] = s;
    int posT = atomicAdd(&cur[NBP + b * Nt + idxt[i]], 1) - NE;
    sTs[posT] = s; sTp[posT] = p28a[i]; sTw[posT] = wt[i];
}

// ---- fused token2map + 3x3 dw s2 conv; half-row blocks, j-outer consume -----
constexpr int RCAP = 512;
__global__ __launch_bounds__(256, 4) void k_gconv(const unsigned short* __restrict__ xh,
        const int* __restrict__ off, const int* __restrict__ srtS,
        const float* __restrict__ dww, unsigned short* __restrict__ convb) {
    __shared__ float sWv[9 * 256];
    __shared__ int   sPk[RCAP];
    __shared__ float sRc[RCAP];
    __shared__ int   sCt[3 * 32];
    __shared__ int   sSt[3 * 32];
    __shared__ int   sSeg[15];
    int blk = blockIdx.x;               // ((b*Ho)+oy)*2 + h
    int h   = blk & 1;
    int boy = blk >> 1;
    int b   = boy / Ho;
    int oy  = boy - b * Ho;
    int c   = threadIdx.x;
    int oxb = h * 14;
    int ix0 = h ? 27 : 0;
    int ncols = h ? 29 : 28;
#pragma unroll
    for (int k = 0; k < 9; ++k) sWv[k * 256 + c] = dww[c * 9 + k];
    if (c < 96) { sCt[c] = 0; sSt[c] = 0; }
    __syncthreads();
    if (c < ncols) {                    // per-column bin ranges (<=3 rows each)
        int ix = ix0 + c;
#pragma unroll
        for (int ky = 0; ky < 3; ++ky) {
            int iy = oy * 2 - 1 + ky;
            if (iy < 0 || iy >= H) continue;
            int bin = b * HW + iy * W + ix;
            int st = off[bin];
            sCt[ky * 32 + c + 1] = off[bin + 1] - st;
            sSt[ky * 32 + c + 1] = st;
        }
    }
    __syncthreads();
    if (c < 14) {                       // expanded per-ox totals
        int tot = 0;
#pragma unroll
        for (int ky = 0; ky < 3; ++ky)
#pragma unroll
            for (int kx = 0; kx < 3; ++kx) {
                int ix = 2 * (oxb + c) - 1 + kx;
                tot += sCt[ky * 32 + (ix - ix0 + 1)];
            }
        sSeg[c] = tot;
    }
    __syncthreads();
    if (c == 0) {
        int a = 0;
#pragma unroll
        for (int k = 0; k < 14; ++k) { int v = sSeg[k]; sSeg[k] = a; a += v; }
        sSeg[14] = a;
    }
    __syncthreads();
    int Ttot = sSeg[14];
    float acc[14];
#pragma unroll
    for (int k = 0; k < 14; ++k) acc[k] = 0.0f;
    const unsigned short* xb = xh + (size_t)b * N * Cin + c;
    for (int r = 0; r < Ttot; r += RCAP) {
        if (c < ncols) {                // cooperative tap-expanded fill
            int ix = ix0 + c;
            int odd = ix & 1;
            int m = ix >> 1;
#pragma unroll
            for (int ky = 0; ky < 3; ++ky) {
                int ct = sCt[ky * 32 + c + 1];
                if (ct == 0) continue;
                int st = sSt[ky * 32 + c + 1];
                float rc = 1.0f / ((float)ct + 1e-6f);
#pragma unroll
                for (int tgt = 0; tgt < 2; ++tgt) {
                    int ox, kx;
                    if (odd) { ox = m + tgt; kx = 2 - 2 * tgt; }
                    else     { if (tgt == 1) break; ox = m; kx = 1; }
                    if (ox < oxb || ox >= oxb + 14) continue;
                    int tap = ky * 3 + kx;
                    int pos = sSeg[ox - oxb];
#pragma unroll
                    for (int ky2 = 0; ky2 < 3; ++ky2)
#pragma unroll
                        for (int kx2 = 0; kx2 < 3; ++kx2) {
                            if (ky2 * 3 + kx2 >= tap) continue;
                            int ix2 = 2 * ox - 1 + kx2;
                            pos += sCt[ky2 * 32 + (ix2 - ix0 + 1)];
                        }
                    int t0 = max(r - pos, 0);
                    int t1 = min(r + RCAP - pos, ct);
                    for (int t = t0; t < t1; ++t) {
                        int idx = pos + t - r;
                        sPk[idx] = srtS[st + t] | (tap << 12);
                        sRc[idx] = rc;
                    }
                }
            }
        }
        __syncthreads();
        int wcnt = min(Ttot - r, RCAP);
        int lo[14], hi[14], maxc = 0;
#pragma unroll
        for (int ox = 0; ox < 14; ++ox) {
            lo[ox] = max(sSeg[ox] - r, 0);
            hi[ox] = min(sSeg[ox + 1] - r, wcnt);
            maxc = max(maxc, hi[ox] - lo[ox]);
        }
        for (int j = 0; j < maxc; ++j) {   // j-outer: 14 independent row loads
#pragma unroll
            for (int ox = 0; ox < 14; ++ox) {
                int pos = lo[ox] + j;
                bool act = pos < hi[ox];
                int pc = act ? pos : 0;
                int pk = sPk[pc];
                float rc = act ? sRc[pc] : 0.0f;
                float xv = bf2f(xb[(size_t)(pk & 0xFFF) * Cin]);
                acc[ox] = fmaf(xv * rc, sWv[(pk >> 12) * 256 + c], acc[ox]);
            }
        }
        __syncthreads();
    }
    size_t obase = ((size_t)b * HWo + oy * Wo + oxb) * Cin + c;
#pragma unroll
    for (int ox = 0; ox < 14; ++ox)
        convb[obase + (size_t)ox * Cin] = f2bf(acc[ox]);
}

// ---- fused map2token + skip + BN1 stats; j-outer/token-inner, no LDS --------
constexpr int TG = 8;
__global__ __launch_bounds__(256, 4) void k_gtok(const unsigned short* __restrict__ xh,
        const unsigned short* __restrict__ convb, const int* __restrict__ off,
        const int* __restrict__ sTs, const int* __restrict__ sTp,
        const float* __restrict__ sTw, const float* __restrict__ skipw,
        unsigned short* __restrict__ ybf, float* __restrict__ s1, float* __restrict__ s1q) {
    int g  = blockIdx.x;
    int c  = threadIdx.x;
    int bt0 = g * TG;
    int b  = bt0 / Nt;                  // 784 % 8 == 0: group stays in one batch
    const unsigned short* xb = xh + (size_t)b * N * Cin + c;
    const unsigned short* cb = convb + (size_t)b * HWo * Cin + c;
    float sk = skipw[c];
    int bnd[TG + 1];
#pragma unroll
    for (int k = 0; k <= TG; ++k) bnd[k] = off[NBP + bt0 + k] - NE;
    int maxc = 0;
#pragma unroll
    for (int k = 0; k < TG; ++k) maxc = max(maxc, bnd[k + 1] - bnd[k]);
    float acc[TG], ws[TG];
#pragma unroll
    for (int k = 0; k < TG; ++k) { acc[k] = 0.0f; ws[k] = 0.0f; }
    for (int j = 0; j < maxc; ++j) {    // j-outer: all tokens' loads independent
#pragma unroll
        for (int k = 0; k < TG; ++k) {
            int pos = bnd[k] + j;
            bool act = pos < bnd[k + 1];
            int pc = min(pos, NE - 1);
            int s = sTs[pc];
            int p = sTp[pc];
            float w = act ? sTw[pc] : 0.0f;
            float cv = bf2f(cb[(size_t)p * Cin]);
            float xv = bf2f(xb[(size_t)s * Cin]);
            ws[k] += w;
            acc[k] = fmaf(w, fmaf(sk, xv, cv), acc[k]);
        }
    }
    float ssum = 0.0f, ssq = 0.0f;
#pragma unroll
    for (int k = 0; k < TG; ++k) {
        float y = acc[k] * (1.0f / (ws[k] + 1e-6f));
        ybf[(size_t)(bt0 + k) * Cin + c] = f2bf(y);
        ssum += y;
        ssq = fmaf(y, y, ssq);
    }
    atomicAdd(&s1[c], ssum);
    atomicAdd(&s1q[c], ssq);
}

// ---- fold BN1 into bf16 weight [Cout][Cin] + fp32 bias ----------------------
__global__ void k_fold(const float* __restrict__ s1, const float* __restrict__ s1q,
                       const float* __restrict__ g1, const float* __restrict__ b1,
                       const float* __restrict__ convw, unsigned short* __restrict__ wfb,
                       float* __restrict__ bias) {
    int o = blockIdx.x, c = threadIdx.x;
    const float inv = 1.0f / (float)RR;
    float mu  = s1[c] * inv;
    float var = s1q[c] * inv - mu * mu;
    float a   = g1[c] / sqrtf(var + 1e-5f);
    float bs  = b1[c] - mu * a;
    float wv  = convw[(size_t)o * Cin + c];
    wfb[(size_t)o * Cin + c] = f2bf(wv * a);
    __shared__ float red[256];
    red[c] = wv * bs;
    __syncthreads();
    for (int st = 128; st > 0; st >>= 1) {
        if (c < st) red[c] += red[c + st];
        __syncthreads();
    }
    if (c == 0) bias[o] = red[0];
}

// ---- bf16 MFMA GEMM with fused BN2 stats; bf16 z out ------------------------
typedef __attribute__((ext_vector_type(8))) short short8;
typedef __attribute__((ext_vector_type(4))) float f32x4;

__global__ __launch_bounds__(256) void k_gemm(const unsigned short* __restrict__ A,
        const unsigned short* __restrict__ Bt, const float* __restrict__ bias,
        unsigned short* __restrict__ zb, float* __restrict__ s2, float* __restrict__ s2q) {
    constexpr int BK = 32, LS = 48;
    __shared__ unsigned short As[128 * LS];
    __shared__ unsigned short Bs[128 * LS];
    __shared__ float rsum[128], rsq[128];
    int m0 = blockIdx.x * 128, n0 = blockIdx.y * 128;
    int t = threadIdx.x;
    int wave = t >> 6, lane = t & 63;
    int wm = wave >> 1, wn = wave & 1;
    int l16 = lane & 15, lq = lane >> 4;
    f32x4 acc[4][4];
#pragma unroll
    for (int i = 0; i < 4; ++i)
#pragma unroll
        for (int j = 0; j < 4; ++j) acc[i][j] = (f32x4)0.0f;
    if (t < 128) { rsum[t] = 0.0f; rsq[t] = 0.0f; }

    for (int k0 = 0; k0 < Cin; k0 += BK) {
#pragma unroll
        for (int r2 = 0; r2 < 2; ++r2) {
            int e = r2 * 256 + t;
            int row = e >> 2, kc = (e & 3) * 8;
            *(float4*)&As[row * LS + kc] = *(const float4*)&A[((size_t)(m0 + row)) * Cin + k0 + kc];
            *(float4*)&Bs[row * LS + kc] = *(const float4*)&Bt[((size_t)(n0 + row)) * Cin + k0 + kc];
        }
        __syncthreads();
        short8 af[4], bf[4];
#pragma unroll
        for (int i = 0; i < 4; ++i) {
            af[i] = *(short8*)&As[(wm * 64 + i * 16 + l16) * LS + lq * 8];
            bf[i] = *(short8*)&Bs[(wn * 64 + i * 16 + l16) * LS + lq * 8];
        }
#pragma unroll
        for (int i = 0; i < 4; ++i)
#pragma unroll
            for (int j = 0; j < 4; ++j)
                acc[i][j] = __builtin_amdgcn_mfma_f32_16x16x32_bf16(af[i], bf[j], acc[i][j], 0, 0, 0);
        __syncthreads();
    }
#pragma unroll
    for (int j = 0; j < 4; ++j) {
        int cl  = wn * 64 + j * 16 + l16;
        int col = n0 + cl;
        float bv = bias[col];
        float ps = 0.0f, pq = 0.0f;
#pragma unroll
        for (int i = 0; i < 4; ++i) {
            int rbase = m0 + wm * 64 + i * 16 + lq * 4;
#pragma unroll
            for (int r = 0; r < 4; ++r) {
                float v = acc[i][j][r] + bv;
                zb[(size_t)(rbase + r) * Cout + col] = f2bf(v);
                ps += v;
                pq = fmaf(v, v, pq);
            }
        }
        atomicAdd(&rsum[cl], ps);
        atomicAdd(&rsq[cl], pq);
    }
    __syncthreads();
    if (t < 128) {
        atomicAdd(&s2[n0 + t], rsum[t]);
        atomicAdd(&s2q[n0 + t], rsq[t]);
    }
}

// ---- BN2 fold + normalize + ReLU (fused): bf16 z -> fp32 out ----------------
__global__ void k_final(const unsigned short* __restrict__ zb, const float* __restrict__ s2,
                        const float* __restrict__ s2q, const float* __restrict__ g2,
                        const float* __restrict__ b2, float* __restrict__ out) {
    size_t j4 = ((size_t)blockIdx.x * 256 + threadIdx.x) * 4;
    int o = (int)(j4 & (Cout - 1));
    const float inv = 1.0f / (float)RR;
    uint2 u = *(const uint2*)&zb[j4];
    float4 r;
#pragma unroll
    for (int k = 0; k < 4; ++k) {
        float mu  = s2[o + k] * inv;
        float var = s2q[o + k] * inv - mu * mu;
        float a   = g2[o + k] / sqrtf(var + 1e-5f);
        float cc  = b2[o + k] - mu * a;
        unsigned short hv = (k < 2) ? (unsigned short)((k & 1) ? (u.x >> 16) : (u.x & 0xffffu))
                                    : (unsigned short)((k & 1) ? (u.y >> 16) : (u.y & 0xffffu));
        float v = fmaf(bf2f(hv), a, cc);
        ((float*)&r)[k] = fmaxf(v, 0.0f);
    }
    *(float4*)&out[j4] = r;
}

extern "C" void kernel_launch(void* const* d_in, const int* in_sizes, int n_in,
                              void* d_out, int out_size, void* d_ws, size_t ws_size,
                              hipStream_t stream) {
    const float* x     = (const float*)d_in[0];
    const float* loc   = (const float*)d_in[1];
    const int*   idxa  = (const int*)d_in[2];
    const int*   idxt  = (const int*)d_in[4];
    const float* wt    = (const float*)d_in[5];
    const float* dww   = (const float*)d_in[9];
    const float* skipw = (const float*)d_in[10];
    const float* convw = (const float*)d_in[11];
    const float* g1    = (const float*)d_in[12];
    const float* b1    = (const float*)d_in[13];
    const float* g2    = (const float*)d_in[14];
    const float* b2    = (const float*)d_in[15];

    float* ws = (float*)d_ws;
    int*   hist  = (int*)(ws + W_HIST);
    float* s1sum = ws + W_S1SUM;
    float* s1sq  = ws + W_S1SQ;
    float* s2sum = ws + W_S2SUM;
    float* s2sq  = ws + W_S2SQ;
    int*   off   = (int*)(ws + W_OFF);
    int*   cur   = (int*)(ws + W_CUR);
    int*   p56a  = (int*)(ws + W_P56);
    int*   p28a  = (int*)(ws + W_P28);
    int*   bsum  = (int*)(ws + W_BSUM);
    int*   srtS  = (int*)(ws + W_SRTS);
    int*   sTs   = (int*)(ws + W_STS);
    int*   sTp   = (int*)(ws + W_STP);
    float* sTw   = ws + W_STW;
    unsigned short* convb = (unsigned short*)(ws + W_CONVB);
    unsigned short* ybf   = (unsigned short*)(ws + W_YBF);
    unsigned short* wfb   = (unsigned short*)(ws + W_WFB);
    float* bias  = ws + W_BIAS;
    unsigned short* zb = (unsigned short*)(ws + W_ZB);
    unsigned short* xh = (unsigned short*)(ws + W_XH);
    float* out   = (float*)d_out;

    hipMemsetAsync(hist, 0, (size_t)(NB + 1536) * sizeof(float), stream);

    k_cast<<<(int)(XTOT / 4 / 256), 256, 0, stream>>>(x, (uint2*)xh);
    k_hist<<<NE / 256, 256, 0, stream>>>(loc, idxt, hist, p56a, p28a);
    k_scanA<<<NCHUNK, 256, 0, stream>>>(hist, bsum);
    k_scanB<<<1, 512, 0, stream>>>(bsum);
    k_scanC<<<NCHUNK, 256, 0, stream>>>(hist, bsum, off, cur);
    k_scatteridx<<<NE / 256, 256, 0, stream>>>(p56a, p28a, idxa, idxt, wt, cur, srtS, sTs, sTp, sTw);

    k_gconv<<<B * Ho * 2, 256, 0, stream>>>(xh, off, srtS, dww, convb);
    k_gtok<<<NBT / TG, 256, 0, stream>>>(xh, convb, off, sTs, sTp, sTw, skipw, ybf, s1sum, s1sq);
    k_fold<<<Cout, 256, 0, stream>>>(s1sum, s1sq, g1, b1, convw, wfb, bias);

    dim3 gg(RR / 128, Cout / 128);
    k_gemm<<<gg, 256, 0, stream>>>(ybf, wfb, bias, zb, s2sum, s2sq);
    k_final<<<(int)(((size_t)RR * Cout) / 1024), 256, 0, stream>>>(zb, s2sum, s2sq, g2, b2, out);
}

// Round 7
// 320.818 us; speedup vs baseline: 1.1270x; 1.1270x over previous
//
#include <hip/hip_runtime.h>

// Problem constants
constexpr int B    = 32;
constexpr int N    = 1568;
constexpr int N0   = 3136;
constexpr int Nt   = 784;
constexpr int Cin  = 256;
constexpr int Cout = 512;
constexpr int H    = 56;
constexpr int W    = 56;
constexpr int HW   = 3136;
constexpr int Ho   = 28;
constexpr int Wo   = 28;
constexpr int HWo  = 784;
constexpr int RR   = B * Nt;      // 25088 GEMM rows
constexpr int NE   = B * N0;      // 100352 entries per index list
constexpr int NBP  = B * HW;      // 100352 pixel bins
constexpr int NBT  = B * Nt;      // 25088 token bins
constexpr int NB   = NBP + NBT;   // 125440 bins
constexpr int NCHUNK = NB / 256;  // 490
constexpr size_t XTOT = (size_t)B * N * Cin;   // 12,845,056 x elements

// Workspace layout (4-byte words). hist + BN stats contiguous -> one memset.
constexpr size_t W_HIST  = 0;                         // NB ints (zeroed)
constexpr size_t W_S1SUM = NB;                        // 256
constexpr size_t W_S1SQ  = W_S1SUM + Cin;             // 256
constexpr size_t W_S2SUM = W_S1SQ + Cin;              // 512
constexpr size_t W_S2SQ  = W_S2SUM + Cout;            // 512 (memset region ends)
constexpr size_t W_OFF   = NB + 1536;                 // NB+1 ints (+pad)
constexpr size_t W_CUR   = W_OFF + NB + 8;            // NB ints
constexpr size_t W_P56   = W_CUR + NB;                // NE ints
constexpr size_t W_P28   = W_P56 + NE;                // NE ints
constexpr size_t W_BSUM  = W_P28 + NE;                // 512 ints
constexpr size_t W_SRTS  = W_BSUM + 512;              // NE ints
constexpr size_t W_STS   = W_SRTS + NE;               // NE ints
constexpr size_t W_STP   = W_STS + NE;                // NE ints
constexpr size_t W_STW   = W_STP + NE;                // NE floats
constexpr size_t W_CONVB = W_STW + NE;                // B*HWo*Cin bf16 -> /2 words
constexpr size_t W_YBF   = W_CONVB + (size_t)B * HWo * Cin / 2;  // RR*Cin bf16
constexpr size_t W_WFB   = W_YBF + (size_t)RR * Cin / 2;         // Cout*Cin bf16
constexpr size_t W_BIAS  = W_WFB + (size_t)Cout * Cin / 2;       // 512
constexpr size_t W_ZB    = W_BIAS + Cout;             // RR*Cout bf16 -> /2 words
constexpr size_t W_XH    = W_ZB + (size_t)RR * Cout / 2;  // XTOT bf16 -> /2 words

__device__ __forceinline__ int pix_of(float t, float scale) {
    t = fminf(fmaxf(t, -1.0f), 1.0f);
    float u = __fadd_rn(__fmul_rn(t, 0.5f), 0.5f);   // no fma contraction
    return (int)rintf(__fmul_rn(u, scale));          // round-half-even == jnp.round
}
__device__ __forceinline__ unsigned short f2bf(float f) {
    unsigned int u = __float_as_uint(f);
    u = (u + 0x7fffu + ((u >> 16) & 1u)) >> 16;      // RNE
    return (unsigned short)u;
}
__device__ __forceinline__ float bf2f(unsigned short h) {
    return __uint_as_float(((unsigned int)h) << 16);
}

// ---- cast x to bf16 ---------------------------------------------------------
__global__ void k_cast(const float* __restrict__ x, uint2* __restrict__ xh2) {
    size_t i = (size_t)blockIdx.x * 256 + threadIdx.x;   // 4 floats per thread
    float4 v = *(const float4*)&x[i * 4];
    uint2 o;
    o.x = (unsigned int)f2bf(v.x) | ((unsigned int)f2bf(v.y) << 16);
    o.y = (unsigned int)f2bf(v.z) | ((unsigned int)f2bf(v.w) << 16);
    xh2[i] = o;
}

// ---- sort phase -------------------------------------------------------------
__global__ void k_hist(const float* __restrict__ loc, const int* __restrict__ idxt,
                       int* __restrict__ hist, int* __restrict__ p56a, int* __restrict__ p28a) {
    int i = blockIdx.x * 256 + threadIdx.x;
    if (i >= NE) return;
    int b = i / N0;
    float lx = loc[(size_t)2 * i], ly = loc[(size_t)2 * i + 1];
    int p56 = pix_of(ly, 55.0f) * W + pix_of(lx, 55.0f);
    int p28 = pix_of(ly, 27.0f) * Wo + pix_of(lx, 27.0f);
    p56a[i] = p56; p28a[i] = p28;
    atomicAdd(&hist[b * HW + p56], 1);
    atomicAdd(&hist[NBP + b * Nt + idxt[i]], 1);
}

__global__ void k_scanA(const int* __restrict__ hist, int* __restrict__ bsum) {
    __shared__ int sm[256];
    int i = blockIdx.x * 256 + threadIdx.x;
    sm[threadIdx.x] = hist[i];
    __syncthreads();
    for (int d = 128; d > 0; d >>= 1) {
        if (threadIdx.x < d) sm[threadIdx.x] += sm[threadIdx.x + d];
        __syncthreads();
    }
    if (threadIdx.x == 0) bsum[blockIdx.x] = sm[0];
}

__global__ void k_scanB(int* __restrict__ bsum) {
    __shared__ int sm[512];
    int t = threadIdx.x;
    int v = (t < NCHUNK) ? bsum[t] : 0;
    sm[t] = v; __syncthreads();
    for (int d = 1; d < 512; d <<= 1) {
        int u = (t >= d) ? sm[t - d] : 0;
        __syncthreads();
        sm[t] += u;
        __syncthreads();
    }
    if (t < NCHUNK) bsum[t] = sm[t] - v;
}

__global__ void k_scanC(const int* __restrict__ hist, const int* __restrict__ bsum,
                        int* __restrict__ off, int* __restrict__ cur) {
    __shared__ int sm[256];
    int t = threadIdx.x;
    int i = blockIdx.x * 256 + t;
    int v = hist[i];
    sm[t] = v; __syncthreads();
    for (int d = 1; d < 256; d <<= 1) {
        int u = (t >= d) ? sm[t - d] : 0;
        __syncthreads();
        sm[t] += u;
        __syncthreads();
    }
    int excl = bsum[blockIdx.x] + sm[t] - v;
    off[i] = excl; cur[i] = excl;
    if (i == NB - 1) off[NB] = excl + v;
}

__global__ void k_scatteridx(const int* __restrict__ p56a, const int* __restrict__ p28a,
                             const int* __restrict__ idxa, const int* __restrict__ idxt,
                             const float* __restrict__ wt, int* __restrict__ cur,
                             int* __restrict__ srtS, int* __restrict__ sTs,
                             int* __restrict__ sTp, float* __restrict__ sTw) {
    int i = blockIdx.x * 256 + threadIdx.x;
    if (i >= NE) return;
    int b = i / N0;
    int s = idxa[i];
    int posP = atomicAdd(&cur[b * HW + p56a[i]], 1);
    srtS[posP] = s;
    int posT = atomicAdd(&cur[NBP + b * Nt + idxt[i]], 1) - NE;
    sTs[posT] = s; sTp[posT] = p28a[i]; sTw[posT] = wt[i];
}

// ---- fused token2map + 3x3 dw s2 conv; half-row blocks, 4-wide consume ------
constexpr int RCAP = 512;
__global__ __launch_bounds__(256, 4) void k_gconv(const unsigned short* __restrict__ xh,
        const int* __restrict__ off, const int* __restrict__ srtS,
        const float* __restrict__ dww, unsigned short* __restrict__ convb) {
    __shared__ float sWv[9 * 256];
    __shared__ int   sPk[RCAP];
    __shared__ float sRc[RCAP];
    __shared__ int   sCt[3 * 32];
    __shared__ int   sSt[3 * 32];
    __shared__ int   sSeg[15];
    int blk = blockIdx.x;               // ((b*Ho)+oy)*2 + h
    int h   = blk & 1;
    int boy = blk >> 1;
    int b   = boy / Ho;
    int oy  = boy - b * Ho;
    int c   = threadIdx.x;
    int oxb = h * 14;
    int ix0 = h ? 27 : 0;
    int ncols = h ? 29 : 28;
#pragma unroll
    for (int k = 0; k < 9; ++k) sWv[k * 256 + c] = dww[c * 9 + k];
    if (c < 96) { sCt[c] = 0; sSt[c] = 0; }
    __syncthreads();
    if (c < ncols) {                    // per-column bin ranges (<=3 rows each)
        int ix = ix0 + c;
#pragma unroll
        for (int ky = 0; ky < 3; ++ky) {
            int iy = oy * 2 - 1 + ky;
            if (iy < 0 || iy >= H) continue;
            int bin = b * HW + iy * W + ix;
            int st = off[bin];
            sCt[ky * 32 + c + 1] = off[bin + 1] - st;
            sSt[ky * 32 + c + 1] = st;
        }
    }
    __syncthreads();
    if (c < 14) {                       // expanded per-ox totals
        int tot = 0;
#pragma unroll
        for (int ky = 0; ky < 3; ++ky)
#pragma unroll
            for (int kx = 0; kx < 3; ++kx) {
                int ix = 2 * (oxb + c) - 1 + kx;
                tot += sCt[ky * 32 + (ix - ix0 + 1)];
            }
        sSeg[c] = tot;
    }
    __syncthreads();
    if (c == 0) {
        int a = 0;
#pragma unroll
        for (int k = 0; k < 14; ++k) { int v = sSeg[k]; sSeg[k] = a; a += v; }
        sSeg[14] = a;
    }
    __syncthreads();
    int Ttot = sSeg[14];
    float acc[14];
#pragma unroll
    for (int k = 0; k < 14; ++k) acc[k] = 0.0f;
    const unsigned short* xb = xh + (size_t)b * N * Cin + c;
    for (int r = 0; r < Ttot; r += RCAP) {
        if (c < ncols) {                // cooperative tap-expanded fill
            int ix = ix0 + c;
            int odd = ix & 1;
            int m = ix >> 1;
#pragma unroll
            for (int ky = 0; ky < 3; ++ky) {
                int ct = sCt[ky * 32 + c + 1];
                if (ct == 0) continue;
                int st = sSt[ky * 32 + c + 1];
                float rc = 1.0f / ((float)ct + 1e-6f);
#pragma unroll
                for (int tgt = 0; tgt < 2; ++tgt) {
                    int ox, kx;
                    if (odd) { ox = m + tgt; kx = 2 - 2 * tgt; }
                    else     { if (tgt == 1) break; ox = m; kx = 1; }
                    if (ox < oxb || ox >= oxb + 14) continue;
                    int tap = ky * 3 + kx;
                    int pos = sSeg[ox - oxb];
#pragma unroll
                    for (int ky2 = 0; ky2 < 3; ++ky2)
#pragma unroll
                        for (int kx2 = 0; kx2 < 3; ++kx2) {
                            if (ky2 * 3 + kx2 >= tap) continue;
                            int ix2 = 2 * ox - 1 + kx2;
                            pos += sCt[ky2 * 32 + (ix2 - ix0 + 1)];
                        }
                    int t0 = max(r - pos, 0);
                    int t1 = min(r + RCAP - pos, ct);
                    for (int t = t0; t < t1; ++t) {
                        int idx = pos + t - r;
                        sPk[idx] = srtS[st + t] | (tap << 12);
                        sRc[idx] = rc;
                    }
                }
            }
        }
        __syncthreads();
        int wcnt = min(Ttot - r, RCAP);
#pragma unroll
        for (int ox = 0; ox < 14; ++ox) {     // R5-proven: 4-wide per segment
            int j0 = max(sSeg[ox] - r, 0);
            int j1 = min(sSeg[ox + 1] - r, wcnt);
            int j = j0;
            for (; j + 4 <= j1; j += 4) {
                int pk0 = sPk[j], pk1 = sPk[j + 1], pk2 = sPk[j + 2], pk3 = sPk[j + 3];
                float r0 = sRc[j], r1 = sRc[j + 1], r2 = sRc[j + 2], r3 = sRc[j + 3];
                float x0 = bf2f(xb[(size_t)(pk0 & 0xFFF) * Cin]);
                float x1 = bf2f(xb[(size_t)(pk1 & 0xFFF) * Cin]);
                float x2 = bf2f(xb[(size_t)(pk2 & 0xFFF) * Cin]);
                float x3 = bf2f(xb[(size_t)(pk3 & 0xFFF) * Cin]);
                acc[ox] = fmaf(x0 * r0, sWv[(pk0 >> 12) * 256 + c], acc[ox]);
                acc[ox] = fmaf(x1 * r1, sWv[(pk1 >> 12) * 256 + c], acc[ox]);
                acc[ox] = fmaf(x2 * r2, sWv[(pk2 >> 12) * 256 + c], acc[ox]);
                acc[ox] = fmaf(x3 * r3, sWv[(pk3 >> 12) * 256 + c], acc[ox]);
            }
            for (; j < j1; ++j) {
                int pk = sPk[j];
                acc[ox] = fmaf(bf2f(xb[(size_t)(pk & 0xFFF) * Cin]) * sRc[j],
                               sWv[(pk >> 12) * 256 + c], acc[ox]);
            }
        }
        __syncthreads();
    }
    size_t obase = ((size_t)b * HWo + oy * Wo + oxb) * Cin + c;
#pragma unroll
    for (int ox = 0; ox < 14; ++ox)
        convb[obase + (size_t)ox * Cin] = f2bf(acc[ox]);
}

// ---- fused map2token + skip; ushort2 channels, 4 tokens/thread-half ---------
constexpr int TG = 8;
__global__ __launch_bounds__(256, 4) void k_gtok(const unsigned short* __restrict__ xh,
        const unsigned short* __restrict__ convb, const int* __restrict__ off,
        const int* __restrict__ sTs, const int* __restrict__ sTp,
        const float* __restrict__ sTw, const float* __restrict__ skipw,
        unsigned int* __restrict__ ybf2) {
    int g   = blockIdx.x;
    int t   = threadIdx.x;
    int hf  = t >> 7;                   // 0: tokens 0-3, 1: tokens 4-7
    int l   = t & 127;                  // channel-pair index
    int ci  = l * 2;
    int bt0 = g * TG;
    int b   = bt0 / Nt;                 // 784 % 8 == 0: group stays in one batch
    const unsigned int* xb = (const unsigned int*)(xh + (size_t)b * N * Cin + ci);
    const unsigned int* cb = (const unsigned int*)(convb + (size_t)b * HWo * Cin + ci);
    float2 sk = *(const float2*)&skipw[ci];
    int bnd[5];
#pragma unroll
    for (int k = 0; k <= 4; ++k) bnd[k] = off[NBP + bt0 + hf * 4 + k] - NE;
    int maxc = 0;
#pragma unroll
    for (int k = 0; k < 4; ++k) maxc = max(maxc, bnd[k + 1] - bnd[k]);
    float ax[4], ay[4], ws[4];
#pragma unroll
    for (int k = 0; k < 4; ++k) { ax[k] = 0.0f; ay[k] = 0.0f; ws[k] = 0.0f; }
    for (int j = 0; j < maxc; ++j) {    // j-outer: 8 independent row loads
#pragma unroll
        for (int k = 0; k < 4; ++k) {
            int pos = bnd[k] + j;
            bool act = pos < bnd[k + 1];
            int pc = act ? pos : max(bnd[k + 1] - 1, 0);   // clamp to last valid: cache hit
            int s = sTs[pc];
            int p = sTp[pc];
            float w = act ? sTw[pc] : 0.0f;
            unsigned int cv = cb[(size_t)p * 128];
            unsigned int xv = xb[(size_t)s * 128];
            float cvx = bf2f((unsigned short)(cv & 0xffffu));
            float cvy = bf2f((unsigned short)(cv >> 16));
            float xvx = bf2f((unsigned short)(xv & 0xffffu));
            float xvy = bf2f((unsigned short)(xv >> 16));
            ws[k] += w;
            ax[k] = fmaf(w, fmaf(sk.x, xvx, cvx), ax[k]);
            ay[k] = fmaf(w, fmaf(sk.y, xvy, cvy), ay[k]);
        }
    }
#pragma unroll
    for (int k = 0; k < 4; ++k) {
        float rw = 1.0f / (ws[k] + 1e-6f);
        unsigned int pk = (unsigned int)f2bf(ax[k] * rw) |
                          ((unsigned int)f2bf(ay[k] * rw) << 16);
        ybf2[(size_t)(bt0 + hf * 4 + k) * 128 + l] = pk;
    }
}

// ---- BN1 stats over bf16 y (separate: low atomic contention) ----------------
__global__ void k_ystats(const unsigned short* __restrict__ ybf,
                         float* __restrict__ s1, float* __restrict__ s1q) {
    int c = threadIdx.x;
    float sum = 0.0f, sq = 0.0f;
    for (int r = blockIdx.x; r < RR; r += gridDim.x) {
        float v = bf2f(ybf[(size_t)r * Cin + c]);
        sum += v;
        sq = fmaf(v, v, sq);
    }
    atomicAdd(&s1[c], sum);
    atomicAdd(&s1q[c], sq);
}

// ---- fold BN1 into bf16 weight [Cout][Cin] + fp32 bias ----------------------
__global__ void k_fold(const float* __restrict__ s1, const float* __restrict__ s1q,
                       const float* __restrict__ g1, const float* __restrict__ b1,
                       const float* __restrict__ convw, unsigned short* __restrict__ wfb,
                       float* __restrict__ bias) {
    int o = blockIdx.x, c = threadIdx.x;
    const float inv = 1.0f / (float)RR;
    float mu  = s1[c] * inv;
    float var = s1q[c] * inv - mu * mu;
    float a   = g1[c] / sqrtf(var + 1e-5f);
    float bs  = b1[c] - mu * a;
    float wv  = convw[(size_t)o * Cin + c];
    wfb[(size_t)o * Cin + c] = f2bf(wv * a);
    __shared__ float red[256];
    red[c] = wv * bs;
    __syncthreads();
    for (int st = 128; st > 0; st >>= 1) {
        if (c < st) red[c] += red[c + st];
        __syncthreads();
    }
    if (c == 0) bias[o] = red[0];
}

// ---- bf16 MFMA GEMM with fused BN2 stats; bf16 z out ------------------------
typedef __attribute__((ext_vector_type(8))) short short8;
typedef __attribute__((ext_vector_type(4))) float f32x4;

__global__ __launch_bounds__(256) void k_gemm(const unsigned short* __restrict__ A,
        const unsigned short* __restrict__ Bt, const float* __restrict__ bias,
        unsigned short* __restrict__ zb, float* __restrict__ s2, float* __restrict__ s2q) {
    constexpr int BK = 32, LS = 48;
    __shared__ unsigned short As[128 * LS];
    __shared__ unsigned short Bs[128 * LS];
    __shared__ float rsum[128], rsq[128];
    int m0 = blockIdx.x * 128, n0 = blockIdx.y * 128;
    int t = threadIdx.x;
    int wave = t >> 6, lane = t & 63;
    int wm = wave >> 1, wn = wave & 1;
    int l16 = lane & 15, lq = lane >> 4;
    f32x4 acc[4][4];
#pragma unroll
    for (int i = 0; i < 4; ++i)
#pragma unroll
        for (int j = 0; j < 4; ++j) acc[i][j] = (f32x4)0.0f;
    if (t < 128) { rsum[t] = 0.0f; rsq[t] = 0.0f; }

    for (int k0 = 0; k0 < Cin; k0 += BK) {
#pragma unroll
        for (int r2 = 0; r2 < 2; ++r2) {
            int e = r2 * 256 + t;
            int row = e >> 2, kc = (e & 3) * 8;
            *(float4*)&As[row * LS + kc] = *(const float4*)&A[((size_t)(m0 + row)) * Cin + k0 + kc];
            *(float4*)&Bs[row * LS + kc] = *(const float4*)&Bt[((size_t)(n0 + row)) * Cin + k0 + kc];
        }
        __syncthreads();
        short8 af[4], bf[4];
#pragma unroll
        for (int i = 0; i < 4; ++i) {
            af[i] = *(short8*)&As[(wm * 64 + i * 16 + l16) * LS + lq * 8];
            bf[i] = *(short8*)&Bs[(wn * 64 + i * 16 + l16) * LS + lq * 8];
        }
#pragma unroll
        for (int i = 0; i < 4; ++i)
#pragma unroll
            for (int j = 0; j < 4; ++j)
                acc[i][j] = __builtin_amdgcn_mfma_f32_16x16x32_bf16(af[i], bf[j], acc[i][j], 0, 0, 0);
        __syncthreads();
    }
#pragma unroll
    for (int j = 0; j < 4; ++j) {
        int cl  = wn * 64 + j * 16 + l16;
        int col = n0 + cl;
        float bv = bias[col];
        float ps = 0.0f, pq = 0.0f;
#pragma unroll
        for (int i = 0; i < 4; ++i) {
            int rbase = m0 + wm * 64 + i * 16 + lq * 4;
#pragma unroll
            for (int r = 0; r < 4; ++r) {
                float v = acc[i][j][r] + bv;
                zb[(size_t)(rbase + r) * Cout + col] = f2bf(v);
                ps += v;
                pq = fmaf(v, v, pq);
            }
        }
        atomicAdd(&rsum[cl], ps);
        atomicAdd(&rsq[cl], pq);
    }
    __syncthreads();
    if (t < 128) {
        atomicAdd(&s2[n0 + t], rsum[t]);
        atomicAdd(&s2q[n0 + t], rsq[t]);
    }
}

// ---- BN2 fold + normalize + ReLU (fused): bf16 z -> fp32 out ----------------
__global__ void k_final(const unsigned short* __restrict__ zb, const float* __restrict__ s2,
                        const float* __restrict__ s2q, const float* __restrict__ g2,
                        const float* __restrict__ b2, float* __restrict__ out) {
    size_t j4 = ((size_t)blockIdx.x * 256 + threadIdx.x) * 4;
    int o = (int)(j4 & (Cout - 1));
    const float inv = 1.0f / (float)RR;
    uint2 u = *(const uint2*)&zb[j4];
    float4 r;
#pragma unroll
    for (int k = 0; k < 4; ++k) {
        float mu  = s2[o + k] * inv;
        float var = s2q[o + k] * inv - mu * mu;
        float a   = g2[o + k] / sqrtf(var + 1e-5f);
        float cc  = b2[o + k] - mu * a;
        unsigned short hv = (k < 2) ? (unsigned short)((k & 1) ? (u.x >> 16) : (u.x & 0xffffu))
                                    : (unsigned short)((k & 1) ? (u.y >> 16) : (u.y & 0xffffu));
        float v = fmaf(bf2f(hv), a, cc);
        ((float*)&r)[k] = fmaxf(v, 0.0f);
    }
    *(float4*)&out[j4] = r;
}

extern "C" void kernel_launch(void* const* d_in, const int* in_sizes, int n_in,
                              void* d_out, int out_size, void* d_ws, size_t ws_size,
                              hipStream_t stream) {
    const float* x     = (const float*)d_in[0];
    const float* loc   = (const float*)d_in[1];
    const int*   idxa  = (const int*)d_in[2];
    const int*   idxt  = (const int*)d_in[4];
    const float* wt    = (const float*)d_in[5];
    const float* dww   = (const float*)d_in[9];
    const float* skipw = (const float*)d_in[10];
    const float* convw = (const float*)d_in[11];
    const float* g1    = (const float*)d_in[12];
    const float* b1    = (const float*)d_in[13];
    const float* g2    = (const float*)d_in[14];
    const float* b2    = (const float*)d_in[15];

    float* ws = (float*)d_ws;
    int*   hist  = (int*)(ws + W_HIST);
    float* s1sum = ws + W_S1SUM;
    float* s1sq  = ws + W_S1SQ;
    float* s2sum = ws + W_S2SUM;
    float* s2sq  = ws + W_S2SQ;
    int*   off   = (int*)(ws + W_OFF);
    int*   cur   = (int*)(ws + W_CUR);
    int*   p56a  = (int*)(ws + W_P56);
    int*   p28a  = (int*)(ws + W_P28);
    int*   bsum  = (int*)(ws + W_BSUM);
    int*   srtS  = (int*)(ws + W_SRTS);
    int*   sTs   = (int*)(ws + W_STS);
    int*   sTp   = (int*)(ws + W_STP);
    float* sTw   = ws + W_STW;
    unsigned short* convb = (unsigned short*)(ws + W_CONVB);
    unsigned short* ybf   = (unsigned short*)(ws + W_YBF);
    unsigned short* wfb   = (unsigned short*)(ws + W_WFB);
    float* bias  = ws + W_BIAS;
    unsigned short* zb = (unsigned short*)(ws + W_ZB);
    unsigned short* xh = (unsigned short*)(ws + W_XH);
    float* out   = (float*)d_out;

    hipMemsetAsync(hist, 0, (size_t)(NB + 1536) * sizeof(float), stream);

    k_cast<<<(int)(XTOT / 4 / 256), 256, 0, stream>>>(x, (uint2*)xh);
    k_hist<<<NE / 256, 256, 0, stream>>>(loc, idxt, hist, p56a, p28a);
    k_scanA<<<NCHUNK, 256, 0, stream>>>(hist, bsum);
    k_scanB<<<1, 512, 0, stream>>>(bsum);
    k_scanC<<<NCHUNK, 256, 0, stream>>>(hist, bsum, off, cur);
    k_scatteridx<<<NE / 256, 256, 0, stream>>>(p56a, p28a, idxa, idxt, wt, cur, srtS, sTs, sTp, sTw);

    k_gconv<<<B * Ho * 2, 256, 0, stream>>>(xh, off, srtS, dww, convb);
    k_gtok<<<NBT / TG, 256, 0, stream>>>(xh, convb, off, sTs, sTp, sTw, skipw, (unsigned int*)ybf);
    k_ystats<<<256, 256, 0, stream>>>(ybf, s1sum, s1sq);
    k_fold<<<Cout, 256, 0, stream>>>(s1sum, s1sq, g1, b1, convw, wfb, bias);

    dim3 gg(RR / 128, Cout / 128);
    k_gemm<<<gg, 256, 0, stream>>>(ybf, wfb, bias, zb, s2sum, s2sq);
    k_final<<<(int)(((size_t)RR * Cout) / 1024), 256, 0, stream>>>(zb, s2sum, s2sq, g2, b2, out);
}

// Round 8
// 314.221 us; speedup vs baseline: 1.1507x; 1.0210x over previous
//
#include <hip/hip_runtime.h>

// Problem constants
constexpr int B    = 32;
constexpr int N    = 1568;
constexpr int N0   = 3136;
constexpr int Nt   = 784;
constexpr int Cin  = 256;
constexpr int Cout = 512;
constexpr int H    = 56;
constexpr int W    = 56;
constexpr int HW   = 3136;
constexpr int Ho   = 28;
constexpr int Wo   = 28;
constexpr int HWo  = 784;
constexpr int RR   = B * Nt;      // 25088 GEMM rows
constexpr int NE   = B * N0;      // 100352 entries per index list
constexpr int NBP  = B * HW;      // 100352 pixel bins
constexpr int NBT  = B * Nt;      // 25088 token bins
constexpr int NB   = NBP + NBT;   // 125440 bins
constexpr int NCHUNK = NB / 256;  // 490
constexpr size_t XTOT = (size_t)B * N * Cin;   // 12,845,056 x elements

// Workspace layout (4-byte words). hist + BN stats contiguous -> one memset.
// avg (51.4 MB) aliases zb (25.7 MB): avg dead before k_gemm writes zb.
constexpr size_t W_HIST  = 0;                         // NB ints (zeroed)
constexpr size_t W_S1SUM = NB;                        // 256
constexpr size_t W_S1SQ  = W_S1SUM + Cin;             // 256
constexpr size_t W_S2SUM = W_S1SQ + Cin;              // 512
constexpr size_t W_S2SQ  = W_S2SUM + Cout;            // 512 (memset region ends)
constexpr size_t W_OFF   = NB + 1536;                 // NB+1 ints (+pad)
constexpr size_t W_CUR   = W_OFF + NB + 8;            // NB ints
constexpr size_t W_P56   = W_CUR + NB;                // NE ints
constexpr size_t W_P28   = W_P56 + NE;                // NE ints
constexpr size_t W_BSUM  = W_P28 + NE;                // 512 ints
constexpr size_t W_SRTS  = W_BSUM + 512;              // NE ints
constexpr size_t W_STS   = W_SRTS + NE;               // NE ints
constexpr size_t W_STP   = W_STS + NE;                // NE ints
constexpr size_t W_STW   = W_STP + NE;                // NE floats
constexpr size_t W_CONVB = W_STW + NE;                // B*HWo*Cin bf16 -> /2 words
constexpr size_t W_YBF   = W_CONVB + (size_t)B * HWo * Cin / 2;  // RR*Cin bf16
constexpr size_t W_WFB   = W_YBF + (size_t)RR * Cin / 2;         // Cout*Cin bf16
constexpr size_t W_BIAS  = W_WFB + (size_t)Cout * Cin / 2;       // 512
constexpr size_t W_ZB    = W_BIAS + Cout;             // RR*Cout bf16 (aliases avg)
constexpr size_t W_AVG   = W_ZB;                      // B*HW*Cin bf16 -> /2 words
constexpr size_t W_XH    = W_AVG + (size_t)B * HW * Cin / 2;   // XTOT bf16

__device__ __forceinline__ int pix_of(float t, float scale) {
    t = fminf(fmaxf(t, -1.0f), 1.0f);
    float u = __fadd_rn(__fmul_rn(t, 0.5f), 0.5f);   // no fma contraction
    return (int)rintf(__fmul_rn(u, scale));          // round-half-even == jnp.round
}
__device__ __forceinline__ unsigned short f2bf(float f) {
    unsigned int u = __float_as_uint(f);
    u = (u + 0x7fffu + ((u >> 16) & 1u)) >> 16;      // RNE
    return (unsigned short)u;
}
__device__ __forceinline__ float bf2f(unsigned short h) {
    return __uint_as_float(((unsigned int)h) << 16);
}

// ---- cast x to bf16 ---------------------------------------------------------
__global__ void k_cast(const float* __restrict__ x, uint2* __restrict__ xh2) {
    size_t i = (size_t)blockIdx.x * 256 + threadIdx.x;   // 4 floats per thread
    float4 v = *(const float4*)&x[i * 4];
    uint2 o;
    o.x = (unsigned int)f2bf(v.x) | ((unsigned int)f2bf(v.y) << 16);
    o.y = (unsigned int)f2bf(v.z) | ((unsigned int)f2bf(v.w) << 16);
    xh2[i] = o;
}

// ---- sort phase -------------------------------------------------------------
__global__ void k_hist(const float* __restrict__ loc, const int* __restrict__ idxt,
                       int* __restrict__ hist, int* __restrict__ p56a, int* __restrict__ p28a) {
    int i = blockIdx.x * 256 + threadIdx.x;
    if (i >= NE) return;
    int b = i / N0;
    float lx = loc[(size_t)2 * i], ly = loc[(size_t)2 * i + 1];
    int p56 = pix_of(ly, 55.0f) * W + pix_of(lx, 55.0f);
    int p28 = pix_of(ly, 27.0f) * Wo + pix_of(lx, 27.0f);
    p56a[i] = p56; p28a[i] = p28;
    atomicAdd(&hist[b * HW + p56], 1);
    atomicAdd(&hist[NBP + b * Nt + idxt[i]], 1);
}

__global__ void k_scanA(const int* __restrict__ hist, int* __restrict__ bsum) {
    __shared__ int sm[256];
    int i = blockIdx.x * 256 + threadIdx.x;
    sm[threadIdx.x] = hist[i];
    __syncthreads();
    for (int d = 128; d > 0; d >>= 1) {
        if (threadIdx.x < d) sm[threadIdx.x] += sm[threadIdx.x + d];
        __syncthreads();
    }
    if (threadIdx.x == 0) bsum[blockIdx.x] = sm[0];
}

__global__ void k_scanB(int* __restrict__ bsum) {
    __shared__ int sm[512];
    int t = threadIdx.x;
    int v = (t < NCHUNK) ? bsum[t] : 0;
    sm[t] = v; __syncthreads();
    for (int d = 1; d < 512; d <<= 1) {
        int u = (t >= d) ? sm[t - d] : 0;
        __syncthreads();
        sm[t] += u;
        __syncthreads();
    }
    if (t < NCHUNK) bsum[t] = sm[t] - v;
}

__global__ void k_scanC(const int* __restrict__ hist, const int* __restrict__ bsum,
                        int* __restrict__ off, int* __restrict__ cur) {
    __shared__ int sm[256];
    int t = threadIdx.x;
    int i = blockIdx.x * 256 + t;
    int v = hist[i];
    sm[t] = v; __syncthreads();
    for (int d = 1; d < 256; d <<= 1) {
        int u = (t >= d) ? sm[t - d] : 0;
        __syncthreads();
        sm[t] += u;
        __syncthreads();
    }
    int excl = bsum[blockIdx.x] + sm[t] - v;
    off[i] = excl; cur[i] = excl;
    if (i == NB - 1) off[NB] = excl + v;
}

__global__ void k_scatteridx(const int* __restrict__ p56a, const int* __restrict__ p28a,
                             const int* __restrict__ idxa, const int* __restrict__ idxt,
                             const float* __restrict__ wt, int* __restrict__ cur,
                             int* __restrict__ srtS, int* __restrict__ sTs,
                             int* __restrict__ sTp, float* __restrict__ sTw) {
    int i = blockIdx.x * 256 + threadIdx.x;
    if (i >= NE) return;
    int b = i / N0;
    int s = idxa[i];
    int posP = atomicAdd(&cur[b * HW + p56a[i]], 1);
    srtS[posP] = s;
    int posT = atomicAdd(&cur[NBP + b * Nt + idxt[i]], 1) - NE;
    sTs[posT] = s; sTp[posT] = p28a[i]; sTw[posT] = wt[i];
}

// ---- sparse stage: averaged dense map (token2map avg), pure TLP -------------
// block = 4 consecutive pixels; 256 thr = 2 slots x 128 ch-pairs; 2 px/thread.
__global__ __launch_bounds__(256) void k_avg(const unsigned short* __restrict__ xh,
        const int* __restrict__ off, const int* __restrict__ srtS,
        unsigned int* __restrict__ avg2) {
    int blk = blockIdx.x;             // bins blk*4 .. blk*4+3 (same batch: 4|HW)
    int t = threadIdx.x;
    int q = t >> 7;                   // pixel slot
    int l = t & 127;                  // channel pair
    int bin0 = blk * 4;
    int b = bin0 / HW;
    const unsigned int* xb = (const unsigned int*)(xh + (size_t)b * N * Cin) + l;
#pragma unroll
    for (int e = 0; e < 2; ++e) {     // two independent pixel chains
        int bin = bin0 + q * 2 + e;
        int st = off[bin], en = off[bin + 1];
        float sx = 0.0f, sy = 0.0f;
        for (int j = st; j < en; ++j) {
            unsigned int v = xb[(size_t)srtS[j] * 128];
            sx += bf2f((unsigned short)(v & 0xffffu));
            sy += bf2f((unsigned short)(v >> 16));
        }
        float rc = 1.0f / ((float)(en - st) + 1e-6f);
        avg2[(size_t)bin * 128 + l] =
            (unsigned int)f2bf(sx * rc) | ((unsigned int)f2bf(sy * rc) << 16);
    }
}

// ---- dense stage: 3x3 dw s2 conv over avg map; regular BW-bound stencil -----
__global__ __launch_bounds__(256) void k_dconv(const unsigned short* __restrict__ avg,
        const float* __restrict__ dww, unsigned short* __restrict__ convb) {
    int blk = blockIdx.x;             // b*Ho + oy
    int b = blk / Ho, oy = blk - b * Ho;
    int c = threadIdx.x;
    float wm[9];
    const unsigned short* rowb[3];
#pragma unroll
    for (int ky = 0; ky < 3; ++ky) {
        int iy = 2 * oy - 1 + ky;
        bool ok = (iy >= 0) && (iy < H);
        int iyc = ok ? iy : 0;
        rowb[ky] = avg + ((size_t)b * HW + (size_t)iyc * W) * Cin;
        float m = ok ? 1.0f : 0.0f;
#pragma unroll
        for (int kx = 0; kx < 3; ++kx) wm[ky * 3 + kx] = dww[c * 9 + ky * 3 + kx] * m;
    }
    size_t obase = ((size_t)b * HWo + (size_t)oy * Wo) * Cin + c;
    {   // ox = 0 (kx=0 tap is out of range)
        float acc = 0.0f;
#pragma unroll
        for (int ky = 0; ky < 3; ++ky)
#pragma unroll
            for (int kx = 1; kx < 3; ++kx)
                acc = fmaf(bf2f(rowb[ky][(size_t)(kx - 1) * Cin + c]), wm[ky * 3 + kx], acc);
        convb[obase] = f2bf(acc);
    }
#pragma unroll 4
    for (int ox = 1; ox < 28; ++ox) { // interior: all taps valid, ix in [1,55]
        float acc = 0.0f;
#pragma unroll
        for (int ky = 0; ky < 3; ++ky)
#pragma unroll
            for (int kx = 0; kx < 3; ++kx)
                acc = fmaf(bf2f(rowb[ky][(size_t)(2 * ox - 1 + kx) * Cin + c]),
                           wm[ky * 3 + kx], acc);
        convb[obase + (size_t)ox * Cin] = f2bf(acc);
    }
}

// ---- map2token + skip; pure TLP gather, 4 tokens/block ----------------------
__global__ __launch_bounds__(256) void k_gtok(const unsigned short* __restrict__ xh,
        const unsigned short* __restrict__ convb, const int* __restrict__ off,
        const int* __restrict__ sTs, const int* __restrict__ sTp,
        const float* __restrict__ sTw, const float* __restrict__ skipw,
        unsigned int* __restrict__ ybf2) {
    int blk = blockIdx.x;             // tokens blk*4 .. +3 (same batch: 4|Nt)
    int t = threadIdx.x;
    int q = t >> 7;                   // token slot
    int l = t & 127;                  // channel pair
    int bt0 = blk * 4;
    int b = bt0 / Nt;
    const unsigned int* xb = (const unsigned int*)(xh + (size_t)b * N * Cin) + l;
    const unsigned int* cb = (const unsigned int*)(convb + (size_t)b * HWo * Cin) + l;
    float2 sk = ((const float2*)skipw)[l];
#pragma unroll
    for (int e = 0; e < 2; ++e) {     // two independent token chains
        int bt = bt0 + q * 2 + e;
        int st = off[NBP + bt] - NE, en = off[NBP + bt + 1] - NE;
        float ax = 0.0f, ay = 0.0f, wsum = 0.0f;
        for (int j = st; j < en; ++j) {
            int s = sTs[j], p = sTp[j];
            float w = sTw[j];
            unsigned int cv = cb[(size_t)p * 128];
            unsigned int xv = xb[(size_t)s * 128];
            wsum += w;
            ax = fmaf(w, fmaf(sk.x, bf2f((unsigned short)(xv & 0xffffu)),
                              bf2f((unsigned short)(cv & 0xffffu))), ax);
            ay = fmaf(w, fmaf(sk.y, bf2f((unsigned short)(xv >> 16)),
                              bf2f((unsigned short)(cv >> 16))), ay);
        }
        float rw = 1.0f / (wsum + 1e-6f);
        ybf2[(size_t)bt * 128 + l] =
            (unsigned int)f2bf(ax * rw) | ((unsigned int)f2bf(ay * rw) << 16);
    }
}

// ---- BN1 stats over bf16 y --------------------------------------------------
__global__ void k_ystats(const unsigned short* __restrict__ ybf,
                         float* __restrict__ s1, float* __restrict__ s1q) {
    int c = threadIdx.x;
    float sum = 0.0f, sq = 0.0f;
    for (int r = blockIdx.x; r < RR; r += gridDim.x) {
        float v = bf2f(ybf[(size_t)r * Cin + c]);
        sum += v;
        sq = fmaf(v, v, sq);
    }
    atomicAdd(&s1[c], sum);
    atomicAdd(&s1q[c], sq);
}

// ---- fold BN1 into bf16 weight [Cout][Cin] + fp32 bias ----------------------
__global__ void k_fold(const float* __restrict__ s1, const float* __restrict__ s1q,
                       const float* __restrict__ g1, const float* __restrict__ b1,
                       const float* __restrict__ convw, unsigned short* __restrict__ wfb,
                       float* __restrict__ bias) {
    int o = blockIdx.x, c = threadIdx.x;
    const float inv = 1.0f / (float)RR;
    float mu  = s1[c] * inv;
    float var = s1q[c] * inv - mu * mu;
    float a   = g1[c] / sqrtf(var + 1e-5f);
    float bs  = b1[c] - mu * a;
    float wv  = convw[(size_t)o * Cin + c];
    wfb[(size_t)o * Cin + c] = f2bf(wv * a);
    __shared__ float red[256];
    red[c] = wv * bs;
    __syncthreads();
    for (int st = 128; st > 0; st >>= 1) {
        if (c < st) red[c] += red[c + st];
        __syncthreads();
    }
    if (c == 0) bias[o] = red[0];
}

// ---- bf16 MFMA GEMM with fused BN2 stats; bf16 z out ------------------------
typedef __attribute__((ext_vector_type(8))) short short8;
typedef __attribute__((ext_vector_type(4))) float f32x4;

__global__ __launch_bounds__(256) void k_gemm(const unsigned short* __restrict__ A,
        const unsigned short* __restrict__ Bt, const float* __restrict__ bias,
        unsigned short* __restrict__ zb, float* __restrict__ s2, float* __restrict__ s2q) {
    constexpr int BK = 32, LS = 48;
    __shared__ unsigned short As[128 * LS];
    __shared__ unsigned short Bs[128 * LS];
    __shared__ float rsum[128], rsq[128];
    int m0 = blockIdx.x * 128, n0 = blockIdx.y * 128;
    int t = threadIdx.x;
    int wave = t >> 6, lane = t & 63;
    int wm = wave >> 1, wn = wave & 1;
    int l16 = lane & 15, lq = lane >> 4;
    f32x4 acc[4][4];
#pragma unroll
    for (int i = 0; i < 4; ++i)
#pragma unroll
        for (int j = 0; j < 4; ++j) acc[i][j] = (f32x4)0.0f;
    if (t < 128) { rsum[t] = 0.0f; rsq[t] = 0.0f; }

    for (int k0 = 0; k0 < Cin; k0 += BK) {
#pragma unroll
        for (int r2 = 0; r2 < 2; ++r2) {
            int e = r2 * 256 + t;
            int row = e >> 2, kc = (e & 3) * 8;
            *(float4*)&As[row * LS + kc] = *(const float4*)&A[((size_t)(m0 + row)) * Cin + k0 + kc];
            *(float4*)&Bs[row * LS + kc] = *(const float4*)&Bt[((size_t)(n0 + row)) * Cin + k0 + kc];
        }
        __syncthreads();
        short8 af[4], bf[4];
#pragma unroll
        for (int i = 0; i < 4; ++i) {
            af[i] = *(short8*)&As[(wm * 64 + i * 16 + l16) * LS + lq * 8];
            bf[i] = *(short8*)&Bs[(wn * 64 + i * 16 + l16) * LS + lq * 8];
        }
#pragma unroll
        for (int i = 0; i < 4; ++i)
#pragma unroll
            for (int j = 0; j < 4; ++j)
                acc[i][j] = __builtin_amdgcn_mfma_f32_16x16x32_bf16(af[i], bf[j], acc[i][j], 0, 0, 0);
        __syncthreads();
    }
#pragma unroll
    for (int j = 0; j < 4; ++j) {
        int cl  = wn * 64 + j * 16 + l16;
        int col = n0 + cl;
        float bv = bias[col];
        float ps = 0.0f, pq = 0.0f;
#pragma unroll
        for (int i = 0; i < 4; ++i) {
            int rbase = m0 + wm * 64 + i * 16 + lq * 4;
#pragma unroll
            for (int r = 0; r < 4; ++r) {
                float v = acc[i][j][r] + bv;
                zb[(size_t)(rbase + r) * Cout + col] = f2bf(v);
                ps += v;
                pq = fmaf(v, v, pq);
            }
        }
        atomicAdd(&rsum[cl], ps);
        atomicAdd(&rsq[cl], pq);
    }
    __syncthreads();
    if (t < 128) {
        atomicAdd(&s2[n0 + t], rsum[t]);
        atomicAdd(&s2q[n0 + t], rsq[t]);
    }
}

// ---- BN2 fold + normalize + ReLU (fused): bf16 z -> fp32 out ----------------
__global__ void k_final(const unsigned short* __restrict__ zb, const float* __restrict__ s2,
                        const float* __restrict__ s2q, const float* __restrict__ g2,
                        const float* __restrict__ b2, float* __restrict__ out) {
    size_t j4 = ((size_t)blockIdx.x * 256 + threadIdx.x) * 4;
    int o = (int)(j4 & (Cout - 1));
    const float inv = 1.0f / (float)RR;
    uint2 u = *(const uint2*)&zb[j4];
    float4 r;
#pragma unroll
    for (int k = 0; k < 4; ++k) {
        float mu  = s2[o + k] * inv;
        float var = s2q[o + k] * inv - mu * mu;
        float a   = g2[o + k] / sqrtf(var + 1e-5f);
        float cc  = b2[o + k] - mu * a;
        unsigned short hv = (k < 2) ? (unsigned short)((k & 1) ? (u.x >> 16) : (u.x & 0xffffu))
                                    : (unsigned short)((k & 1) ? (u.y >> 16) : (u.y & 0xffffu));
        float v = fmaf(bf2f(hv), a, cc);
        ((float*)&r)[k] = fmaxf(v, 0.0f);
    }
    *(float4*)&out[j4] = r;
}

extern "C" void kernel_launch(void* const* d_in, const int* in_sizes, int n_in,
                              void* d_out, int out_size, void* d_ws, size_t ws_size,
                              hipStream_t stream) {
    const float* x     = (const float*)d_in[0];
    const float* loc   = (const float*)d_in[1];
    const int*   idxa  = (const int*)d_in[2];
    const int*   idxt  = (const int*)d_in[4];
    const float* wt    = (const float*)d_in[5];
    const float* dww   = (const float*)d_in[9];
    const float* skipw = (const float*)d_in[10];
    const float* convw = (const float*)d_in[11];
    const float* g1    = (const float*)d_in[12];
    const float* b1    = (const float*)d_in[13];
    const float* g2    = (const float*)d_in[14];
    const float* b2    = (const float*)d_in[15];

    float* ws = (float*)d_ws;
    int*   hist  = (int*)(ws + W_HIST);
    float* s1sum = ws + W_S1SUM;
    float* s1sq  = ws + W_S1SQ;
    float* s2sum = ws + W_S2SUM;
    float* s2sq  = ws + W_S2SQ;
    int*   off   = (int*)(ws + W_OFF);
    int*   cur   = (int*)(ws + W_CUR);
    int*   p56a  = (int*)(ws + W_P56);
    int*   p28a  = (int*)(ws + W_P28);
    int*   bsum  = (int*)(ws + W_BSUM);
    int*   srtS  = (int*)(ws + W_SRTS);
    int*   sTs   = (int*)(ws + W_STS);
    int*   sTp   = (int*)(ws + W_STP);
    float* sTw   = ws + W_STW;
    unsigned short* convb = (unsigned short*)(ws + W_CONVB);
    unsigned short* ybf   = (unsigned short*)(ws + W_YBF);
    unsigned short* wfb   = (unsigned short*)(ws + W_WFB);
    float* bias  = ws + W_BIAS;
    unsigned short* zb  = (unsigned short*)(ws + W_ZB);
    unsigned short* avg = (unsigned short*)(ws + W_AVG);   // aliases zb region
    unsigned short* xh  = (unsigned short*)(ws + W_XH);
    float* out   = (float*)d_out;

    hipMemsetAsync(hist, 0, (size_t)(NB + 1536) * sizeof(float), stream);

    k_cast<<<(int)(XTOT / 4 / 256), 256, 0, stream>>>(x, (uint2*)xh);
    k_hist<<<NE / 256, 256, 0, stream>>>(loc, idxt, hist, p56a, p28a);
    k_scanA<<<NCHUNK, 256, 0, stream>>>(hist, bsum);
    k_scanB<<<1, 512, 0, stream>>>(bsum);
    k_scanC<<<NCHUNK, 256, 0, stream>>>(hist, bsum, off, cur);
    k_scatteridx<<<NE / 256, 256, 0, stream>>>(p56a, p28a, idxa, idxt, wt, cur, srtS, sTs, sTp, sTw);

    k_avg<<<NBP / 4, 256, 0, stream>>>(xh, off, srtS, (unsigned int*)avg);
    k_dconv<<<B * Ho, 256, 0, stream>>>(avg, dww, convb);
    k_gtok<<<NBT / 4, 256, 0, stream>>>(xh, convb, off, sTs, sTp, sTw, skipw, (unsigned int*)ybf);
    k_ystats<<<256, 256, 0, stream>>>(ybf, s1sum, s1sq);
    k_fold<<<Cout, 256, 0, stream>>>(s1sum, s1sq, g1, b1, convw, wfb, bias);

    dim3 gg(RR / 128, Cout / 128);
    k_gemm<<<gg, 256, 0, stream>>>(ybf, wfb, bias, zb, s2sum, s2sq);
    k_final<<<(int)(((size_t)RR * Cout) / 1024), 256, 0, stream>>>(zb, s2sum, s2sq, g2, b2, out);
}